// Round 2
// baseline (10810.741 us; speedup 1.0000x reference)
//
#include <hip/hip_runtime.h>
#include <cmath>

#define SDIM 64
#define BDIM 64
#define KDIM 512
#define HDIM 512
#define EDIM 512
#define ADIM 512
#define VDIM 32000
#define TSTEPS 32
#define NBLK 256
#define NLOG 500   // logits tasks (V tiles of 64)
#define PSTR 512   // psum/pmax/pidx row stride (>= NLOG)

// ================= grid barrier (sense-reversing, device scope) =================
__device__ __forceinline__ void gbar(unsigned* cnt, unsigned* gen) {
  __syncthreads();
  if (threadIdx.x == 0) {
    __threadfence();   // release: publish this block's stores (L2 writeback, agent scope)
    unsigned g = __hip_atomic_load(gen, __ATOMIC_RELAXED, __HIP_MEMORY_SCOPE_AGENT);
    unsigned a = __hip_atomic_fetch_add(cnt, 1u, __ATOMIC_ACQ_REL, __HIP_MEMORY_SCOPE_AGENT);
    if (a == NBLK - 1u) {
      __hip_atomic_store(cnt, 0u, __ATOMIC_RELAXED, __HIP_MEMORY_SCOPE_AGENT);
      __hip_atomic_store(gen, g + 1u, __ATOMIC_RELEASE, __HIP_MEMORY_SCOPE_AGENT);
    } else {
      while (__hip_atomic_load(gen, __ATOMIC_RELAXED, __HIP_MEMORY_SCOPE_AGENT) == g)
        __builtin_amdgcn_s_sleep(2);
    }
    __threadfence();   // acquire: invalidate caches so subsequent loads see remote data
  }
  __syncthreads();
}

// ================= init: h0 (transposed), x0 = emb[SOS], inv_sum = 1, barrier = 0 =================
__global__ __launch_bounds__(256) void k_init(const float* __restrict__ efs,
                                              const float* __restrict__ emb,
                                              float* __restrict__ hA,
                                              float* __restrict__ xT,
                                              float* __restrict__ inv_sum,
                                              unsigned* __restrict__ bar) {
  int idx = blockIdx.x * 256 + threadIdx.x;
  if (idx < HDIM * BDIM) {
    int i = idx >> 6, b = idx & 63;
    hA[idx] = efs[b * HDIM + i];
    xT[idx] = emb[1 * EDIM + i];   // SOS = 1
  }
  if (idx < BDIM) inv_sum[idx] = 1.0f;
  if (idx < 2) bar[idx] = 0u;
}

// ================= build Wg[1536][1536]: rows 0..1023 = W_ih^T, rows 1024..1535 = W_hh^T =================
__global__ __launch_bounds__(256) void k_buildWg(const float* __restrict__ Wih,
                                                 const float* __restrict__ Whh,
                                                 float* __restrict__ Wg) {
  __shared__ float t[32][33];
  int k0 = blockIdx.x * 32;
  int j0 = blockIdx.y * 32;
  const float* src;
  int ldi, scol;
  if (k0 < 1024) { src = Wih; ldi = 1024; scol = k0; }
  else           { src = Whh; ldi = 512;  scol = k0 - 1024; }
  int tid = threadIdx.x;
#pragma unroll
  for (int i = 0; i < 4; ++i) {
    int e = tid + i * 256, r = e >> 5, c = e & 31;
    t[r][c] = src[(size_t)(j0 + r) * ldi + scol + c];
  }
  __syncthreads();
#pragma unroll
  for (int i = 0; i < 4; ++i) {
    int e = tid + i * 256, r = e >> 5, c = e & 31;
    Wg[(size_t)(k0 + r) * 1536 + j0 + c] = t[c][r];
  }
}

// ================= keys_proj = enc(4096x512) @ Wk(512x512), one-time =================
__global__ __launch_bounds__(256) void k_keysproj(const float* __restrict__ enc,
                                                  const float* __restrict__ Wk,
                                                  float* __restrict__ kp) {
  __shared__ float As[16][65];
  __shared__ float Bs[16][64];
  int m0 = blockIdx.x * 64;
  int n0 = blockIdx.y * 64;
  int tid = threadIdx.x;
  int tm = tid >> 4, tn = tid & 15;
  float acc[4][4] = {};
  for (int k0 = 0; k0 < KDIM; k0 += 16) {
    for (int l = tid; l < 1024; l += 256) {
      int m = l >> 4, kk = l & 15;
      As[kk][m] = enc[(size_t)(m0 + m) * KDIM + k0 + kk];
    }
    for (int l = tid; l < 1024; l += 256) {
      int kk = l >> 6, n = l & 63;
      Bs[kk][n] = Wk[(size_t)(k0 + kk) * ADIM + n0 + n];
    }
    __syncthreads();
#pragma unroll
    for (int kk = 0; kk < 16; ++kk) {
      float a[4], w[4];
#pragma unroll
      for (int i = 0; i < 4; ++i) a[i] = As[kk][tm * 4 + i];
#pragma unroll
      for (int j = 0; j < 4; ++j) w[j] = Bs[kk][tn * 4 + j];
#pragma unroll
      for (int i = 0; i < 4; ++i)
#pragma unroll
        for (int j = 0; j < 4; ++j) acc[i][j] += a[i] * w[j];
    }
    __syncthreads();
  }
  for (int i = 0; i < 4; ++i)
    for (int j = 0; j < 4; ++j)
      kp[(size_t)(m0 + tm * 4 + i) * ADIM + n0 + tn * 4 + j] = acc[i][j];
}

// ================= GEMM core on caller-provided LDS: C[n][b] 64x64 = sum_k A_T[k][b]*W[k][n] =================
template <int KLEN>
__device__ __forceinline__ void dev_gemm(const float* __restrict__ A,
                                         const float* __restrict__ W, int ldw,
                                         float* __restrict__ Cout,
                                         float* __restrict__ SM) {
  float* As = SM;          // [32][64]
  float* Ws = SM + 2048;   // [32][64]
  int tid = threadIdx.x;
  int tn = tid >> 4, tb = tid & 15;
  float acc[4][4] = {};
  float ra[8], rw[8];
#pragma unroll
  for (int t = 0; t < 8; ++t) {
    int l = tid + t * 256, kk = l >> 6, c = l & 63;
    ra[t] = A[kk * 64 + c];
    rw[t] = W[(size_t)kk * ldw + c];
  }
  for (int k0 = 0; k0 < KLEN; k0 += 32) {
#pragma unroll
    for (int t = 0; t < 8; ++t) {
      int l = tid + t * 256, kk = l >> 6, c = l & 63;
      As[kk * 64 + c] = ra[t];
      Ws[kk * 64 + c] = rw[t];
    }
    __syncthreads();
    if (k0 + 32 < KLEN) {
#pragma unroll
      for (int t = 0; t < 8; ++t) {
        int l = tid + t * 256, kk = l >> 6, c = l & 63;
        ra[t] = A[(k0 + 32 + kk) * 64 + c];
        rw[t] = W[(size_t)(k0 + 32 + kk) * ldw + c];
      }
    }
#pragma unroll
    for (int kk = 0; kk < 32; ++kk) {
      float4 a = *(const float4*)&As[kk * 64 + tb * 4];
      float4 w = *(const float4*)&Ws[kk * 64 + tn * 4];
      acc[0][0] += w.x * a.x; acc[0][1] += w.x * a.y; acc[0][2] += w.x * a.z; acc[0][3] += w.x * a.w;
      acc[1][0] += w.y * a.x; acc[1][1] += w.y * a.y; acc[1][2] += w.y * a.z; acc[1][3] += w.y * a.w;
      acc[2][0] += w.z * a.x; acc[2][1] += w.z * a.y; acc[2][2] += w.z * a.z; acc[2][3] += w.z * a.w;
      acc[3][0] += w.w * a.x; acc[3][1] += w.w * a.y; acc[3][2] += w.w * a.z; acc[3][3] += w.w * a.w;
    }
    __syncthreads();
  }
#pragma unroll
  for (int i = 0; i < 4; ++i)
#pragma unroll
    for (int j = 0; j < 4; ++j)
      Cout[(tn * 4 + i) * 64 + tb * 4 + j] = acc[i][j];
}

// ================= initial qW partials (4 K-quarters); grid 32 =================
__global__ __launch_bounds__(256) void k_qw_init(const float* __restrict__ hA,
                                                 const float* __restrict__ Wq,
                                                 float* __restrict__ qWp) {
  __shared__ float SM[4096];
  int j = blockIdx.x, nt = j >> 2, kq = j & 3;
  dev_gemm<128>(hA + kq * 128 * 64, Wq + (size_t)(kq * 128) * ADIM + nt * 64, ADIM,
                qWp + ((size_t)kq * 512 + nt * 64) * 64, SM);
}

// ================= attention task (one per b) =================
__device__ __forceinline__ void dev_attn(int b, const float* __restrict__ kp,
                                         const float* __restrict__ enc,
                                         const float* __restrict__ qWp,
                                         const float* __restrict__ vatt,
                                         float* __restrict__ cT, float* SM) {
  float* qw = SM;          // 512
  float* va = SM + 512;    // 512
  float* scp = SM + 1024;  // 256
  float* atw = SM + 1280;  // 64
  int tid = threadIdx.x;
  for (int i = tid; i < ADIM; i += 256) {
    qw[i] = qWp[i * 64 + b] + qWp[32768 + i * 64 + b] +
            qWp[65536 + i * 64 + b] + qWp[98304 + i * 64 + b];
    va[i] = vatt[i];
  }
  __syncthreads();
  int s = tid >> 2, q = tid & 3;
  const float* row = kp + (size_t)(s * BDIM + b) * ADIM;
  float p = 0.f;
  for (int it = 0; it < 32; ++it) {
    int a = q * 4 + it * 16;
    float4 kv = *(const float4*)(row + a);
    float4 qv = *(const float4*)(qw + a);
    float4 vv = *(const float4*)(va + a);
    p += vv.x * tanhf(qv.x + kv.x);
    p += vv.y * tanhf(qv.y + kv.y);
    p += vv.z * tanhf(qv.z + kv.z);
    p += vv.w * tanhf(qv.w + kv.w);
  }
  scp[s * 4 + q] = p;
  __syncthreads();
  if (tid < 64) {
    float v = (scp[tid * 4] + scp[tid * 4 + 1]) + (scp[tid * 4 + 2] + scp[tid * 4 + 3]);
    float m = v;
#pragma unroll
    for (int o = 32; o > 0; o >>= 1) m = fmaxf(m, __shfl_xor(m, o, 64));
    float e = expf(v - m);
    float ssum = e;
#pragma unroll
    for (int o = 32; o > 0; o >>= 1) ssum += __shfl_xor(ssum, o, 64);
    atw[tid] = e / ssum;
  }
  __syncthreads();
  for (int k = tid; k < KDIM; k += 256) {
    float acc = 0.f;
#pragma unroll 4
    for (int s2 = 0; s2 < SDIM; ++s2) acc += atw[s2] * enc[(size_t)(s2 * BDIM + b) * KDIM + k];
    cT[k * 64 + b] = acc;
  }
}

// ================= logits task: 64-wide V tile gemm + exp + partials + norm of prev slice =================
__device__ __forceinline__ void dev_logits(int vt, int t, int tprev,
                                           const float* __restrict__ hidT,
                                           const float* __restrict__ W2,
                                           const float* __restrict__ b2,
                                           float* __restrict__ out,
                                           const float* __restrict__ inv_sum,
                                           float* __restrict__ psum,
                                           float* __restrict__ pmax,
                                           int* __restrict__ pidx,
                                           float* SM) {
  float* As = SM;           // 2048
  float* Bs = SM + 2048;    // 2048
  int*   Ri = (int*)(SM + 4096); // 2048
  int vbase = vt * 64;
  int tid = threadIdx.x;
  int trow = tid >> 5, tcol = tid & 31;
  int m0 = trow * 8, n0 = tcol * 2;

  // normalize previous step's slice (this thread's exact elements)
#pragma unroll
  for (int mi = 0; mi < 8; ++mi) {
    int b = m0 + mi;
    float inv = inv_sum[b];
    float2* p = (float2*)(out + (size_t)(b * TSTEPS + tprev) * VDIM + vbase + n0);
    float2 v = *p;
    v.x *= inv; v.y *= inv;
    *p = v;
  }

  float pa[8], pb[8];
#pragma unroll
  for (int tt = 0; tt < 8; ++tt) {
    int l = tid + tt * 256;
    pa[tt] = hidT[(l >> 6) * 64 + (l & 63)];
    pb[tt] = W2[(size_t)(l >> 6) * VDIM + vbase + (l & 63)];
  }

  float accT[8][2] = {};
  for (int k0 = 0; k0 < 512; k0 += 32) {
#pragma unroll
    for (int tt = 0; tt < 8; ++tt) {
      int l = tid + tt * 256;
      As[(l >> 6) * 64 + (l & 63)] = pa[tt];
      Bs[(l >> 6) * 64 + (l & 63)] = pb[tt];
    }
    __syncthreads();
    if (k0 + 32 < 512) {
#pragma unroll
      for (int tt = 0; tt < 8; ++tt) {
        int l = tid + tt * 256;
        pa[tt] = hidT[(k0 + 32 + (l >> 6)) * 64 + (l & 63)];
        pb[tt] = W2[(size_t)(k0 + 32 + (l >> 6)) * VDIM + vbase + (l & 63)];
      }
    }
#pragma unroll
    for (int kk = 0; kk < 32; ++kk) {
      float4 a0 = *(const float4*)&As[kk * 64 + m0];
      float4 a1 = *(const float4*)&As[kk * 64 + m0 + 4];
      float2 w = *(const float2*)&Bs[kk * 64 + n0];
      float am[8] = {a0.x, a0.y, a0.z, a0.w, a1.x, a1.y, a1.z, a1.w};
#pragma unroll
      for (int mi = 0; mi < 8; ++mi) {
        accT[mi][0] += am[mi] * w.x;
        accT[mi][1] += am[mi] * w.y;
      }
    }
    __syncthreads();
  }

  float2 bb = *(const float2*)(b2 + vbase + n0);
  float lsum[8], lmax[8];
  int limx[8];
#pragma unroll
  for (int mi = 0; mi < 8; ++mi) {
    int b = m0 + mi;
    float e0 = expf(accT[mi][0] + bb.x);
    float e1 = expf(accT[mi][1] + bb.y);
    float2 ev = {e0, e1};
    *(float2*)(out + (size_t)(b * TSTEPS + t) * VDIM + vbase + n0) = ev;
    lsum[mi] = e0 + e1;
    if (e0 >= e1) { lmax[mi] = e0; limx[mi] = vbase + n0; }
    else          { lmax[mi] = e1; limx[mi] = vbase + n0 + 1; }
  }

#pragma unroll
  for (int mi = 0; mi < 8; ++mi) {
    int b = m0 + mi;
    As[b * 32 + tcol] = lsum[mi];
    Bs[b * 32 + tcol] = lmax[mi];
    Ri[b * 32 + tcol] = limx[mi];
  }
  __syncthreads();
  if (tid < 64) {
    float s = 0, mx = -__builtin_inff();
    int mix = 0x7fffffff;
    for (int c = 0; c < 32; ++c) {
      s += As[tid * 32 + c];
      float v = Bs[tid * 32 + c];
      if (v > mx) { mx = v; mix = Ri[tid * 32 + c]; }
    }
    psum[tid * PSTR + vt] = s;
    pmax[tid * PSTR + vt] = mx;
    pidx[tid * PSTR + vt] = mix;
  }
  __syncthreads();   // LDS WAR guard before next task reuses SM
}

// ================= finish task (one per b) =================
__device__ __forceinline__ void dev_finish(int b, const float* __restrict__ psum,
                                           const float* __restrict__ pmax,
                                           const int* __restrict__ pidx,
                                           const float* __restrict__ emb,
                                           float* __restrict__ invs,
                                           float* __restrict__ xT, float* SM) {
  int tid = threadIdx.x;
  float* ssum = SM;
  float* smax = SM + 256;
  int* sidx = (int*)(SM + 512);
  int* stok = (int*)(SM + 768);
  float s = psum[b * PSTR + tid];
  float m = pmax[b * PSTR + tid];
  int ix = pidx[b * PSTR + tid];
  int j = tid + 256;
  if (j < NLOG) {
    float s2 = psum[b * PSTR + j];
    float m2 = pmax[b * PSTR + j];
    int i2 = pidx[b * PSTR + j];
    s += s2;
    if (m2 > m || (m2 == m && i2 < ix)) { m = m2; ix = i2; }
  }
  ssum[tid] = s; smax[tid] = m; sidx[tid] = ix;
  __syncthreads();
  for (int st = 128; st > 0; st >>= 1) {
    if (tid < st) {
      ssum[tid] += ssum[tid + st];
      float v2 = smax[tid + st];
      int i2 = sidx[tid + st];
      if (v2 > smax[tid] || (v2 == smax[tid] && i2 < sidx[tid])) {
        smax[tid] = v2; sidx[tid] = i2;
      }
    }
    __syncthreads();
  }
  if (tid == 0) { invs[b] = 1.0f / ssum[0]; *stok = sidx[0]; }
  __syncthreads();
  int tok = *stok;
  for (int i = tid; i < EDIM; i += 256) xT[i * 64 + b] = emb[(size_t)tok * EDIM + i];
}

// ================= THE persistent step-loop kernel (grid must be exactly NBLK) =================
__global__ __launch_bounds__(256, 1) void k_loop(const float* __restrict__ enc,
                                                 const float* __restrict__ emb,
                                                 const float* __restrict__ Wq,
                                                 const float* __restrict__ vatt,
                                                 const float* __restrict__ Wg,
                                                 const float* __restrict__ bih,
                                                 const float* __restrict__ bhh,
                                                 const float* __restrict__ W1,
                                                 const float* __restrict__ b1,
                                                 const float* __restrict__ W2,
                                                 const float* __restrict__ b2,
                                                 float* __restrict__ out,
                                                 const float* __restrict__ kp,
                                                 float* __restrict__ catT,
                                                 float* __restrict__ hA,
                                                 float* __restrict__ hB,
                                                 float* __restrict__ qWp,
                                                 float* __restrict__ hidT,
                                                 float* __restrict__ Gp,
                                                 float* __restrict__ Hp,
                                                 float* __restrict__ psum,
                                                 float* __restrict__ pmax,
                                                 int* __restrict__ pidx,
                                                 float* __restrict__ invs,
                                                 unsigned* __restrict__ bar) {
  __shared__ float SM[6144];   // 24 KB, reused per phase
  const int blk = blockIdx.x;
  const int tid = threadIdx.x;
  unsigned* cnt = bar;
  unsigned* gen = bar + 1;
  float* xT = catT;
  float* cS = catT + 512 * 64;
  const int GS = 1536 * 64;    // Gp plane stride
  const int HS = 512 * 64;     // Hp / qWp plane stride

  for (int t = 0; t < TSTEPS; ++t) {
    const float* hOld = (t & 1) ? hB : hA;
    float* hNew = (t & 1) ? hA : hB;

    // ---- PA: attn(0-63) | gates_x(64-111) | gates_h(112-159) | mlp1_x(160-175) ----
    if (blk < 64) {
      dev_attn(blk, kp, enc, qWp, vatt, cS, SM);
    } else if (blk < 112) {
      int j = blk - 64, nt = j >> 1, kh = j & 1;
      dev_gemm<256>(catT + kh * 256 * 64, Wg + (size_t)(kh * 256) * 1536 + nt * 64, 1536,
                    Gp + (size_t)kh * GS + (size_t)(nt * 64) * 64, SM);
    } else if (blk < 160) {
      int j = blk - 112, nt = j >> 1, kh = j & 1;
      dev_gemm<256>(hOld + kh * 256 * 64, Wg + (size_t)(1024 + kh * 256) * 1536 + nt * 64, 1536,
                    Gp + (size_t)(6 + kh) * GS + (size_t)(nt * 64) * 64, SM);
    } else if (blk < 176) {
      int j = blk - 160, nt = j >> 1, kh = j & 1;
      dev_gemm<256>(catT + kh * 256 * 64, W1 + (size_t)(kh * 256) * 512 + nt * 64, 512,
                    Hp + (size_t)kh * HS + (size_t)(nt * 64) * 64, SM);
    }
    gbar(cnt, gen);

    // ---- PB: gates_ctx(0-95, K=128 quarters) | mlp1_ctx(96-127) ----
    if (blk < 96) {
      int nt = blk >> 2, kq = blk & 3;
      dev_gemm<128>(cS + kq * 128 * 64, Wg + (size_t)(512 + kq * 128) * 1536 + nt * 64, 1536,
                    Gp + (size_t)(2 + kq) * GS + (size_t)(nt * 64) * 64, SM);
    } else if (blk < 128) {
      int j = blk - 96, nt = j >> 2, kq = j & 3;
      dev_gemm<128>(cS + kq * 128 * 64, W1 + (size_t)(1024 + kq * 128) * 512 + nt * 64, 512,
                    Hp + (size_t)(2 + kq) * HS + (size_t)(nt * 64) * 64, SM);
    }
    gbar(cnt, gen);

    // ---- PC: GRU nonlinearity (8 Gp planes: gi = 0..5, gh = 6..7) ----
    if (tid < 128) {
      int idx = blk * 128 + tid;   // 32768
      int u = idx >> 6;
      int o_r = idx;
      int o_z = idx + 512 * 64;
      int o_n = idx + 1024 * 64;
      float gi_r = 0.f, gi_z = 0.f, gi_n = 0.f;
#pragma unroll
      for (int p = 0; p < 6; ++p) {
        gi_r += Gp[(size_t)p * GS + o_r];
        gi_z += Gp[(size_t)p * GS + o_z];
        gi_n += Gp[(size_t)p * GS + o_n];
      }
      float gh_r = Gp[(size_t)6 * GS + o_r] + Gp[(size_t)7 * GS + o_r];
      float gh_z = Gp[(size_t)6 * GS + o_z] + Gp[(size_t)7 * GS + o_z];
      float gh_n = Gp[(size_t)6 * GS + o_n] + Gp[(size_t)7 * GS + o_n];
      float r = 1.f / (1.f + expf(-(gi_r + bih[u] + gh_r + bhh[u])));
      float z = 1.f / (1.f + expf(-(gi_z + bih[512 + u] + gh_z + bhh[512 + u])));
      float n = tanhf(gi_n + bih[1024 + u] + r * (gh_n + bhh[1024 + u]));
      hNew[idx] = (1.f - z) * n + z * hOld[idx];
    }
    gbar(cnt, gen);

    // ---- PD: mlp1_h(0-31, K=128) | qW next (32-63, K=128) ----
    if (blk < 32) {
      int nt = blk >> 2, kq = blk & 3;
      dev_gemm<128>(hNew + kq * 128 * 64, W1 + (size_t)(512 + kq * 128) * 512 + nt * 64, 512,
                    Hp + (size_t)(6 + kq) * HS + (size_t)(nt * 64) * 64, SM);
    } else if (blk < 64) {
      int j = blk - 32, nt = j >> 2, kq = j & 3;
      dev_gemm<128>(hNew + kq * 128 * 64, Wq + (size_t)(kq * 128) * ADIM + nt * 64, ADIM,
                    qWp + (size_t)kq * HS + (size_t)(nt * 64) * 64, SM);
    }
    gbar(cnt, gen);

    // ---- PE: hid reduce (10 Hp planes) ----
    if (tid < 128) {
      int idx = blk * 128 + tid;
      float s = b1[idx >> 6];
#pragma unroll
      for (int p = 0; p < 10; ++p) s += Hp[(size_t)p * HS + idx];
      hidT[idx] = tanhf(s);
    }
    gbar(cnt, gen);

    // ---- PF: logits (500 tasks) + normalize prev slice ----
    {
      int tprev = (t == 0) ? 0 : t - 1;
      for (int v = blk; v < NLOG; v += NBLK)
        dev_logits(v, t, tprev, hidT, W2, b2, out, invs, psum, pmax, pidx, SM);
    }
    gbar(cnt, gen);

    // ---- PG: finish (argmax -> token -> xT, inv_sum) ----
    if (blk < 64) dev_finish(blk, psum, pmax, pidx, emb, invs, xT, SM);
    gbar(cnt, gen);
  }

  // ---- final normalization of step T-1 ----
  for (int idx = blk * 256 + tid; idx < 512000; idx += NBLK * 256) {
    int b = idx / 8000, v4 = idx % 8000;
    float inv = invs[b];
    float4* p = (float4*)(out + (size_t)(b * TSTEPS + (TSTEPS - 1)) * VDIM) + v4;
    float4 v = *p;
    v.x *= inv; v.y *= inv; v.z *= inv; v.w *= inv;
    *p = v;
  }
}

extern "C" void kernel_launch(void* const* d_in, const int* in_sizes, int n_in,
                              void* d_out, int out_size, void* d_ws, size_t ws_size,
                              hipStream_t stream) {
  const float* enc  = (const float*)d_in[0];
  const float* efs  = (const float*)d_in[1];
  const float* emb  = (const float*)d_in[2];
  const float* Wq   = (const float*)d_in[3];
  const float* Wk   = (const float*)d_in[4];
  const float* vatt = (const float*)d_in[5];
  const float* Wih  = (const float*)d_in[6];
  const float* Whh  = (const float*)d_in[7];
  const float* bih  = (const float*)d_in[8];
  const float* bhh  = (const float*)d_in[9];
  const float* W1   = (const float*)d_in[10];
  const float* b1   = (const float*)d_in[11];
  const float* W2   = (const float*)d_in[12];
  const float* b2   = (const float*)d_in[13];
  float* out = (float*)d_out;

  float* ws = (float*)d_ws;
  float* kp   = ws;                      // 2,097,152
  float* Wg   = kp + 2097152;            // 2,359,296
  float* catT = Wg + 2359296;            // 65,536 (xT rows 0..511 | cS rows 512..1023)
  float* hA   = catT + 65536;            // 32,768
  float* hB   = hA + 32768;              // 32,768
  float* qWp  = hB + 32768;              // 131,072 (4 planes)
  float* hidT = qWp + 131072;            // 32,768
  float* Gp   = hidT + 32768;            // 786,432 (8 x 1536 x 64)
  float* Hp   = Gp + 786432;             // 327,680 (10 x 512 x 64)
  float* psum = Hp + 327680;             // 32,768 (64 x 512)
  float* pmax = psum + 32768;            // 32,768
  int* pidx   = (int*)(pmax + 32768);    // 32,768
  float* invs = (float*)(pidx + 32768);  // 64
  unsigned* bar = (unsigned*)(invs + 64);// 2

  k_init<<<128, 256, 0, stream>>>(efs, emb, hA, catT, invs, bar);
  k_buildWg<<<dim3(48, 48), 256, 0, stream>>>(Wih, Whh, Wg);
  k_keysproj<<<dim3(64, 8), 256, 0, stream>>>(enc, Wk, kp);
  k_qw_init<<<32, 256, 0, stream>>>(hA, Wq, qWp);
  k_loop<<<NBLK, 256, 0, stream>>>(enc, emb, Wq, vatt, Wg, bih, bhh, W1, b1, W2, b2,
                                   out, kp, catT, hA, hB, qWp, hidT, Gp, Hp,
                                   psum, pmax, pidx, invs, bar);
}